// Round 1
// baseline (2682.119 us; speedup 1.0000x reference)
//
#include <hip/hip_runtime.h>
#include <hip/hip_bf16.h>

// MusicRNN: 2-layer LSTM (B=2048, T=256, I=88, H=64) + FC(64->13), fp32.
// Structure: per-batch-row independence -> 256 blocks x 8 rows, two kernels
// (layer0 writes ys1 to a static device buffer; layer1 consumes it + FC).
// Weights live in dynamic LDS (permuted [k][hh*4+gate] for ds_read_b128);
// x / ys1 stream through scalar loads (wave-uniform addresses).

#define B_ 2048
#define T_ 256
#define I_ 88
#define H_ 64
#define O_ 13
#define NB 8          // rows per block
#define G4H 256       // 4*H

// ys1[t][row][hh], fp32
__device__ __align__(16) float g_ys1[(size_t)T_ * B_ * H_];
// permuted weights: [88*256] ih0 | [64*256] hh0 | [64*256] ih1 | [64*256] hh1
__device__ __align__(16) float g_wp[(I_ + H_ + H_ + H_) * G4H];

__device__ __forceinline__ float sigmoid_f(float v) {
    return 1.f / (1.f + __expf(-v));
}
__device__ __forceinline__ float tanh_f(float v) {
    // 1 - 2/(e^{2v}+1); saturates correctly for |v| large
    return 1.f - 2.f / (__expf(2.f * v) + 1.f);
}

// -------- prep: permute weights into [k][hh*4+gate] layouts --------
__global__ void prep_weights(const float* __restrict__ wih0, const float* __restrict__ whh0,
                             const float* __restrict__ wih1, const float* __restrict__ whh1) {
    int id = blockIdx.x * blockDim.x + threadIdx.x;
    const int S0 = I_ * G4H;            // 22528
    const int S1 = S0 + H_ * G4H;       // +16384
    const int S2 = S1 + H_ * G4H;
    const int S3 = S2 + H_ * G4H;
    if (id >= S3) return;
    const float* src;
    int base, K;
    if (id < S0)      { base = 0;  src = wih0; K = I_; }
    else if (id < S1) { base = S0; src = whh0; K = H_; }
    else if (id < S2) { base = S1; src = wih1; K = H_; }
    else              { base = S2; src = whh1; K = H_; }
    int loc = id - base;
    int k   = loc >> 8;        // /256
    int col = loc & 255;
    int hh  = col >> 2;
    int g   = col & 3;         // 0:i 1:f 2:g 3:o  (PyTorch row j = g*64+hh)
    g_wp[id] = src[(g * H_ + hh) * K + k];
}

// -------- layer 0 --------
__global__ __launch_bounds__(256, 1) void lstm_l0(const float* __restrict__ x,
                                                  const float* __restrict__ bih,
                                                  const float* __restrict__ bhh) {
    extern __shared__ float sm[];
    float* w0  = sm;                 // [88][256]
    float* wh  = sm + I_ * G4H;      // [64][256]
    float* hsh = sm + (I_ + H_) * G4H; // [2][8][64]

    const int tid = threadIdx.x;
    // stage weights (152*256 floats = 9728 float4)
    for (int i = tid; i < ((I_ + H_) * G4H) / 4; i += 256)
        ((float4*)sm)[i] = ((const float4*)g_wp)[i];
    for (int i = tid; i < NB * H_; i += 256) hsh[i] = 0.f; // zero h buf0

    const int hh = tid & 63;
    const int rg = __builtin_amdgcn_readfirstlane(tid >> 6); // wave-uniform
    const int row0 = blockIdx.x * NB + rg * 2;
    const float* xr0 = x + (size_t)row0 * (T_ * I_);
    const float* xr1 = xr0 + (T_ * I_);

    const float b0 = bih[hh] + bhh[hh];
    const float b1 = bih[64 + hh] + bhh[64 + hh];
    const float b2 = bih[128 + hh] + bhh[128 + hh];
    const float b3 = bih[192 + hh] + bhh[192 + hh];

    float c0 = 0.f, c1 = 0.f;
    float* ys0 = g_ys1 + (size_t)row0 * H_ + hh;  // + t*B_*H_

    __syncthreads();

    for (int t = 0; t < T_; ++t) {
        float a00 = b0, a01 = b1, a02 = b2, a03 = b3;
        float a10 = b0, a11 = b1, a12 = b2, a13 = b3;
        const float* xt0 = xr0 + t * I_;
        const float* xt1 = xr1 + t * I_;
#pragma unroll 8
        for (int k = 0; k < I_; ++k) {
            const float4 w = *(const float4*)&w0[(k << 8) + (hh << 2)];
            const float xv0 = xt0[k];
            const float xv1 = xt1[k];
            a00 += w.x * xv0; a01 += w.y * xv0; a02 += w.z * xv0; a03 += w.w * xv0;
            a10 += w.x * xv1; a11 += w.y * xv1; a12 += w.z * xv1; a13 += w.w * xv1;
        }
        const float* hc = hsh + (t & 1) * (NB * H_) + rg * 128;
#pragma unroll 8
        for (int k = 0; k < H_; ++k) {
            const float4 w = *(const float4*)&wh[(k << 8) + (hh << 2)];
            const float hv0 = hc[k];
            const float hv1 = hc[64 + k];
            a00 += w.x * hv0; a01 += w.y * hv0; a02 += w.z * hv0; a03 += w.w * hv0;
            a10 += w.x * hv1; a11 += w.y * hv1; a12 += w.z * hv1; a13 += w.w * hv1;
        }
        // gates: 0=i 1=f 2=g 3=o
        const float i0 = sigmoid_f(a00), f0 = sigmoid_f(a01), g0 = tanh_f(a02), o0 = sigmoid_f(a03);
        const float i1 = sigmoid_f(a10), f1 = sigmoid_f(a11), g1 = tanh_f(a12), o1 = sigmoid_f(a13);
        c0 = f0 * c0 + i0 * g0;
        c1 = f1 * c1 + i1 * g1;
        const float h0 = o0 * tanh_f(c0);
        const float h1 = o1 * tanh_f(c1);
        float* hn = hsh + ((t + 1) & 1) * (NB * H_) + rg * 128 + hh;
        hn[0]  = h0;
        hn[64] = h1;
        float* yb = ys0 + (size_t)t * (B_ * H_);
        yb[0]  = h0;
        yb[64] = h1;
        __syncthreads();
    }
}

// -------- layer 1 + FC --------
__global__ __launch_bounds__(256, 1) void lstm_l1(const float* __restrict__ bih,
                                                  const float* __restrict__ bhh,
                                                  const float* __restrict__ fcw,
                                                  const float* __restrict__ fcb,
                                                  float* __restrict__ out) {
    extern __shared__ float sm[];
    float* wi  = sm;                 // [64][256]
    float* wh  = sm + H_ * G4H;      // [64][256]
    float* hsh = sm + 2 * H_ * G4H;  // [2][8][64]

    const int tid = threadIdx.x;
    const float* wp1 = g_wp + (I_ + H_) * G4H;
    for (int i = tid; i < (2 * H_ * G4H) / 4; i += 256)
        ((float4*)sm)[i] = ((const float4*)wp1)[i];
    for (int i = tid; i < NB * H_; i += 256) hsh[i] = 0.f;

    const int hh = tid & 63;
    const int rg = __builtin_amdgcn_readfirstlane(tid >> 6);
    const int row0 = blockIdx.x * NB + rg * 2;

    const float b0 = bih[hh] + bhh[hh];
    const float b1 = bih[64 + hh] + bhh[64 + hh];
    const float b2 = bih[128 + hh] + bhh[128 + hh];
    const float b3 = bih[192 + hh] + bhh[192 + hh];

    float c0 = 0.f, c1 = 0.f;
    const float* yr = g_ys1 + (size_t)row0 * H_;  // + t*B_*H_ ; [k] row0, [64+k] row0+1

    __syncthreads();

    for (int t = 0; t < T_; ++t) {
        float a00 = b0, a01 = b1, a02 = b2, a03 = b3;
        float a10 = b0, a11 = b1, a12 = b2, a13 = b3;
        const float* yt = yr + (size_t)t * (B_ * H_);
#pragma unroll 8
        for (int k = 0; k < H_; ++k) {
            const float4 w = *(const float4*)&wi[(k << 8) + (hh << 2)];
            const float yv0 = yt[k];
            const float yv1 = yt[64 + k];
            a00 += w.x * yv0; a01 += w.y * yv0; a02 += w.z * yv0; a03 += w.w * yv0;
            a10 += w.x * yv1; a11 += w.y * yv1; a12 += w.z * yv1; a13 += w.w * yv1;
        }
        const float* hc = hsh + (t & 1) * (NB * H_) + rg * 128;
#pragma unroll 8
        for (int k = 0; k < H_; ++k) {
            const float4 w = *(const float4*)&wh[(k << 8) + (hh << 2)];
            const float hv0 = hc[k];
            const float hv1 = hc[64 + k];
            a00 += w.x * hv0; a01 += w.y * hv0; a02 += w.z * hv0; a03 += w.w * hv0;
            a10 += w.x * hv1; a11 += w.y * hv1; a12 += w.z * hv1; a13 += w.w * hv1;
        }
        const float i0 = sigmoid_f(a00), f0 = sigmoid_f(a01), g0 = tanh_f(a02), o0 = sigmoid_f(a03);
        const float i1 = sigmoid_f(a10), f1 = sigmoid_f(a11), g1 = tanh_f(a12), o1 = sigmoid_f(a13);
        c0 = f0 * c0 + i0 * g0;
        c1 = f1 * c1 + i1 * g1;
        const float h0 = o0 * tanh_f(c0);
        const float h1 = o1 * tanh_f(c1);
        float* hn = hsh + ((t + 1) & 1) * (NB * H_) + rg * 128 + hh;
        hn[0]  = h0;
        hn[64] = h1;
        __syncthreads();
    }

    // FC: h_last lives in hsh buf[(T_)&1 == 0]
    const float* hl = hsh;  // [8][64]
    if (tid < NB * O_) {
        const int r = tid / O_;
        const int o = tid % O_;
        float s = fcb[o];
        const float* wrow = fcw + o * H_;
#pragma unroll 8
        for (int k = 0; k < H_; ++k) s += hl[r * H_ + k] * wrow[k];
        out[(size_t)(blockIdx.x * NB + r) * O_ + o] = s;
    }
}

extern "C" void kernel_launch(void* const* d_in, const int* in_sizes, int n_in,
                              void* d_out, int out_size, void* d_ws, size_t ws_size,
                              hipStream_t stream) {
    const float* x     = (const float*)d_in[0];
    const float* wih0  = (const float*)d_in[1];
    const float* whh0  = (const float*)d_in[2];
    const float* bih0  = (const float*)d_in[3];
    const float* bhh0  = (const float*)d_in[4];
    const float* wih1  = (const float*)d_in[5];
    const float* whh1  = (const float*)d_in[6];
    const float* bih1  = (const float*)d_in[7];
    const float* bhh1  = (const float*)d_in[8];
    const float* fcw   = (const float*)d_in[9];
    const float* fcb   = (const float*)d_in[10];
    float* out = (float*)d_out;

    const int lds0 = (I_ + H_) * G4H * 4 + 2 * NB * H_ * 4;   // 155648 + 2048 = 157696
    const int lds1 = 2 * H_ * G4H * 4 + 2 * NB * H_ * 4;      // 131072 + 2048 = 133120
    hipFuncSetAttribute((const void*)lstm_l0, hipFuncAttributeMaxDynamicSharedMemorySize, lds0);
    hipFuncSetAttribute((const void*)lstm_l1, hipFuncAttributeMaxDynamicSharedMemorySize, lds1);

    prep_weights<<<dim3(280), dim3(256), 0, stream>>>(wih0, whh0, wih1, whh1);
    lstm_l0<<<dim3(B_ / NB), dim3(256), lds0, stream>>>(x, bih0, bhh0);
    lstm_l1<<<dim3(B_ / NB), dim3(256), lds1, stream>>>(bih1, bhh1, fcw, fcb, out);
}

// Round 4
// 2453.196 us; speedup vs baseline: 1.0933x; 1.0933x over previous
//
#include <hip/hip_runtime.h>
#include <hip/hip_bf16.h>

// MusicRNN: 2-layer LSTM (B=2048, T=256, I=88, H=64) + FC(64->13), fp32.
// v4: interleaved time-chunked two-phase design (TC=32, 8 chunks):
//   per chunk: gemm_l0 -> lstm_rec(L0) -> gemm_l1 -> lstm_rec(L1)
//   gemm_*   : input projection, weights in dynamic LDS (plain kernels,
//              round-1-proven hipFuncSetAttribute path), 32 FMA chains/thread
//   lstm_rec : h@W_hh only; W_hh row in VGPRs (64 regs), gate exchange in LDS;
//              h,c carried across chunk kernels in small global buffers.
// Static device footprint kept at ~82 MB (round-1 proved 129 MB works).

#define B_ 2048
#define T_ 256
#define I_ 88
#define H_ 64
#define O_ 13
#define G4H 256           // 4*H
#define TC 32             // time chunk
#define CR (B_ * TC)      // rows per chunk = 65536
#define NCK (T_ / TC)     // 8 chunks

// chunk-local pre-activations [tl][b][gate*64+h], 64 MB
__device__ __align__(16) float g_gpre[(size_t)CR * G4H];
// chunk-local layer-0 hidden states [tl][b][h], 16 MB
__device__ __align__(16) float g_ysc[(size_t)CR * H_];
// permuted GEMM weights: [88*256] ih0 | [64*256] ih1, layout [k][hh*4+g]
__device__ __align__(16) float g_wp[(I_ + H_) * G4H];
// h,c carried across chunk kernels, per layer
__device__ float g_h[2][B_ * H_];
__device__ float g_c[2][B_ * H_];

__device__ __forceinline__ float sigmoid_f(float v) {
    return 1.f / (1.f + __expf(-v));
}
__device__ __forceinline__ float tanh_f(float v) {
    return 1.f - 2.f / (__expf(2.f * v) + 1.f);
}

// -------- prep: permute W_ih0, W_ih1 into [k][hh*4+gate] --------
__global__ void prep_weights(const float* __restrict__ wih0, const float* __restrict__ wih1) {
    int id = blockIdx.x * blockDim.x + threadIdx.x;
    const int S0 = I_ * G4H;             // 22528
    const int S1 = S0 + H_ * G4H;        // 38912
    if (id >= S1) return;
    const float* src;
    int base, K;
    if (id < S0) { base = 0;  src = wih0; K = I_; }
    else         { base = S0; src = wih1; K = H_; }
    int loc = id - base;
    int k   = loc >> 8;
    int col = loc & 255;
    int hh  = col >> 2;
    int g   = col & 3;                   // 0:i 1:f 2:g 3:o
    g_wp[id] = src[(g * H_ + hh) * K + k];
}

// -------- layer-0 chunk GEMM: gpre[q][g*64+h] = x[row(q)] @ Wih0^T --------
// q = tl*B + b (tl = q>>11, b = q&2047); x row = b*T + ck*TC + tl.
__global__ __launch_bounds__(256, 1) void gemm_l0(const float* __restrict__ x, int ck) {
    extern __shared__ __align__(16) float wl[];   // [88][256]
    const int tid = threadIdx.x;
    for (int i = tid; i < (I_ * G4H) / 4; i += 256)
        ((float4*)wl)[i] = ((const float4*)g_wp)[i];
    __syncthreads();

    const int j  = tid & 63;
    const int wv = __builtin_amdgcn_readfirstlane(tid >> 6);

    for (int p = 0; p < 8; ++p) {
        const int qb = (blockIdx.x << 8) + (p << 5) + (wv << 3);
        const float* xr[8];
#pragma unroll
        for (int m = 0; m < 8; ++m) {
            const int q = qb + m;
            const long in_row = (long)(q & (B_ - 1)) * T_ + ck * TC + (q >> 11);
            xr[m] = x + (size_t)in_row * I_;
        }
        float4 acc[8];
#pragma unroll
        for (int m = 0; m < 8; ++m) acc[m] = make_float4(0.f, 0.f, 0.f, 0.f);

#pragma unroll 2
        for (int k = 0; k < I_; ++k) {
            const float4 w4 = *(const float4*)&wl[(k << 8) + (j << 2)];
#pragma unroll
            for (int m = 0; m < 8; ++m) {
                const float xv = xr[m][k];
                acc[m].x += w4.x * xv; acc[m].y += w4.y * xv;
                acc[m].z += w4.z * xv; acc[m].w += w4.w * xv;
            }
        }
#pragma unroll
        for (int m = 0; m < 8; ++m) {
            float* o = g_gpre + (size_t)(qb + m) * G4H + j;
            o[0]   = acc[m].x;   // gate i
            o[64]  = acc[m].y;   // gate f
            o[128] = acc[m].z;   // gate g
            o[192] = acc[m].w;   // gate o
        }
    }
}

// -------- layer-1 chunk GEMM: gpre[q][g*64+h] = ysc[q] @ Wih1^T --------
__global__ __launch_bounds__(256, 1) void gemm_l1() {
    extern __shared__ __align__(16) float wl[];   // [64][256]
    const int tid = threadIdx.x;
    for (int i = tid; i < (H_ * G4H) / 4; i += 256)
        ((float4*)wl)[i] = ((const float4*)(g_wp + I_ * G4H))[i];
    __syncthreads();

    const int j  = tid & 63;
    const int wv = __builtin_amdgcn_readfirstlane(tid >> 6);

    for (int p = 0; p < 8; ++p) {
        const int qb = (blockIdx.x << 8) + (p << 5) + (wv << 3);
        const float* xr[8];
#pragma unroll
        for (int m = 0; m < 8; ++m) xr[m] = g_ysc + (size_t)(qb + m) * H_;

        float4 acc[8];
#pragma unroll
        for (int m = 0; m < 8; ++m) acc[m] = make_float4(0.f, 0.f, 0.f, 0.f);

#pragma unroll 2
        for (int k = 0; k < H_; ++k) {
            const float4 w4 = *(const float4*)&wl[(k << 8) + (j << 2)];
#pragma unroll
            for (int m = 0; m < 8; ++m) {
                const float xv = xr[m][k];
                acc[m].x += w4.x * xv; acc[m].y += w4.y * xv;
                acc[m].z += w4.z * xv; acc[m].w += w4.w * xv;
            }
        }
#pragma unroll
        for (int m = 0; m < 8; ++m) {
            float* o = g_gpre + (size_t)(qb + m) * G4H + j;
            o[0]   = acc[m].x;
            o[64]  = acc[m].y;
            o[128] = acc[m].z;
            o[192] = acc[m].w;
        }
    }
}

// -------- recurrence for one chunk: one row per block, one gate per wave --------
__global__ __launch_bounds__(256, 1) void lstm_rec(const float* __restrict__ whh,
                                                   const float* __restrict__ bih,
                                                   const float* __restrict__ bhh,
                                                   const int layer, const int ck,
                                                   const float* __restrict__ fcw,
                                                   const float* __restrict__ fcb,
                                                   float* __restrict__ out) {
    __shared__ __align__(16) float hl[H_];
    __shared__ float xch[4][H_];

    const int tid = threadIdx.x;
    const int j   = tid & 63;
    const int g   = __builtin_amdgcn_readfirstlane(tid >> 6);
    const int r   = blockIdx.x;

    // W_hh row (g*64+j) into VGPRs: 64 floats = 16 float4
    float4 w[16];
    const float* wrow = whh + (size_t)(g * H_ + j) * H_;
#pragma unroll
    for (int kk = 0; kk < 16; ++kk) w[kk] = ((const float4*)wrow)[kk];

    const float bias = bih[g * H_ + j] + bhh[g * H_ + j];
    if (tid < H_) hl[tid] = ck ? g_h[layer][r * H_ + tid] : 0.f;
    float c = 0.f;
    if (g == 0 && ck) c = g_c[layer][r * H_ + j];

    const float* gp = g_gpre + (size_t)r * G4H + g * H_ + j;  // + tl*B_*G4H
    float gpv = gp[0];
    __syncthreads();

    for (int tl = 0; tl < TC; ++tl) {
        float a0 = 0.f, a1 = 0.f, a2 = 0.f, a3 = 0.f;
#pragma unroll
        for (int kk = 0; kk < 16; kk += 4) {
            const float4 h0 = *(const float4*)&hl[(kk + 0) << 2];
            a0 += w[kk + 0].x * h0.x; a0 += w[kk + 0].y * h0.y;
            a0 += w[kk + 0].z * h0.z; a0 += w[kk + 0].w * h0.w;
            const float4 h1 = *(const float4*)&hl[(kk + 1) << 2];
            a1 += w[kk + 1].x * h1.x; a1 += w[kk + 1].y * h1.y;
            a1 += w[kk + 1].z * h1.z; a1 += w[kk + 1].w * h1.w;
            const float4 h2 = *(const float4*)&hl[(kk + 2) << 2];
            a2 += w[kk + 2].x * h2.x; a2 += w[kk + 2].y * h2.y;
            a2 += w[kk + 2].z * h2.z; a2 += w[kk + 2].w * h2.w;
            const float4 h3 = *(const float4*)&hl[(kk + 3) << 2];
            a3 += w[kk + 3].x * h3.x; a3 += w[kk + 3].y * h3.y;
            a3 += w[kk + 3].z * h3.z; a3 += w[kk + 3].w * h3.w;
        }
        const float pre = bias + gpv + ((a0 + a1) + (a2 + a3));
        if (tl + 1 < TC) gpv = gp[(size_t)(tl + 1) * B_ * G4H];  // prefetch

        const float act = (g == 2) ? tanh_f(pre) : sigmoid_f(pre);
        xch[g][j] = act;
        __syncthreads();

        if (g == 0) {
            const float iv = xch[0][j], fv = xch[1][j], gv = xch[2][j], ov = xch[3][j];
            c = fv * c + iv * gv;
            const float h = ov * tanh_f(c);
            hl[j] = h;
            if (layer == 0) g_ysc[((size_t)tl * B_ + r) * H_ + j] = h;
        }
        __syncthreads();
    }

    if (g == 0) {
        g_h[layer][r * H_ + j] = hl[j];
        g_c[layer][r * H_ + j] = c;
        if (layer == 1 && ck == NCK - 1 && j < O_) {
            float s = fcb[j];
            const float* wr = fcw + j * H_;
#pragma unroll
            for (int k = 0; k < H_; ++k) s += hl[k] * wr[k];
            out[(size_t)r * O_ + j] = s;
        }
    }
}

extern "C" void kernel_launch(void* const* d_in, const int* in_sizes, int n_in,
                              void* d_out, int out_size, void* d_ws, size_t ws_size,
                              hipStream_t stream) {
    const float* x    = (const float*)d_in[0];
    const float* wih0 = (const float*)d_in[1];
    const float* whh0 = (const float*)d_in[2];
    const float* bih0 = (const float*)d_in[3];
    const float* bhh0 = (const float*)d_in[4];
    const float* wih1 = (const float*)d_in[5];
    const float* whh1 = (const float*)d_in[6];
    const float* bih1 = (const float*)d_in[7];
    const float* bhh1 = (const float*)d_in[8];
    const float* fcw  = (const float*)d_in[9];
    const float* fcb  = (const float*)d_in[10];
    float* out = (float*)d_out;

    const int lds0 = I_ * G4H * 4;   // 90112
    const int lds1 = H_ * G4H * 4;   // 65536
    hipFuncSetAttribute((const void*)gemm_l0, hipFuncAttributeMaxDynamicSharedMemorySize, lds0);
    hipFuncSetAttribute((const void*)gemm_l1, hipFuncAttributeMaxDynamicSharedMemorySize, lds1);

    prep_weights<<<dim3(152), dim3(256), 0, stream>>>(wih0, wih1);

    for (int ck = 0; ck < NCK; ++ck) {
        gemm_l0<<<dim3(CR / 256), dim3(256), lds0, stream>>>(x, ck);
        lstm_rec<<<dim3(B_), dim3(256), 0, stream>>>(whh0, bih0, bhh0, 0, ck, fcw, fcb, out);
        gemm_l1<<<dim3(CR / 256), dim3(256), lds1, stream>>>();
        lstm_rec<<<dim3(B_), dim3(256), 0, stream>>>(whh1, bih1, bhh1, 1, ck, fcw, fcb, out);
    }
}

// Round 6
// 2415.696 us; speedup vs baseline: 1.1103x; 1.0155x over previous
//
#include <hip/hip_runtime.h>
#include <hip/hip_bf16.h>

// MusicRNN: 2-layer LSTM (B=2048, T=256, I=88, H=64) + FC(64->13), fp32.
// v5: v4 with restructured recurrence (GEMM phase unchanged).
//   lstm_rec: 4 rows/block (256 thr). Wave g = gate g for all 4 rows,
//   outer-product over k: per k one broadcast b128 of hl[k][0..3] feeds
//   4 FMAs against the wave's VGPR-resident W_hh row. Combine phase uses
//   all 256 threads (thread (r,j) owns c). 512 blocks -> 2 blocks/CU.

#define B_ 2048
#define T_ 256
#define I_ 88
#define H_ 64
#define O_ 13
#define G4H 256           // 4*H
#define TC 32             // time chunk
#define CR (B_ * TC)      // rows per chunk = 65536
#define NCK (T_ / TC)     // 8 chunks
#define NBR 4             // rows per rec block

// chunk-local pre-activations [tl][b][gate*64+h], 64 MB
__device__ __align__(16) float g_gpre[(size_t)CR * G4H];
// chunk-local layer-0 hidden states [tl][b][h], 16 MB
__device__ __align__(16) float g_ysc[(size_t)CR * H_];
// permuted GEMM weights: [88*256] ih0 | [64*256] ih1, layout [k][hh*4+g]
__device__ __align__(16) float g_wp[(I_ + H_) * G4H];
// h,c carried across chunk kernels, per layer
__device__ float g_h[2][B_ * H_];
__device__ float g_c[2][B_ * H_];

__device__ __forceinline__ float sigmoid_f(float v) {
    return 1.f / (1.f + __expf(-v));
}
__device__ __forceinline__ float tanh_f(float v) {
    return 1.f - 2.f / (__expf(2.f * v) + 1.f);
}

// -------- prep: permute W_ih0, W_ih1 into [k][hh*4+gate] --------
__global__ void prep_weights(const float* __restrict__ wih0, const float* __restrict__ wih1) {
    int id = blockIdx.x * blockDim.x + threadIdx.x;
    const int S0 = I_ * G4H;             // 22528
    const int S1 = S0 + H_ * G4H;        // 38912
    if (id >= S1) return;
    const float* src;
    int base, K;
    if (id < S0) { base = 0;  src = wih0; K = I_; }
    else         { base = S0; src = wih1; K = H_; }
    int loc = id - base;
    int k   = loc >> 8;
    int col = loc & 255;
    int hh  = col >> 2;
    int g   = col & 3;                   // 0:i 1:f 2:g 3:o
    g_wp[id] = src[(g * H_ + hh) * K + k];
}

// -------- layer-0 chunk GEMM: gpre[q][g*64+h] = x[row(q)] @ Wih0^T --------
// q = tl*B + b (tl = q>>11, b = q&2047); x row = b*T + ck*TC + tl.
__global__ __launch_bounds__(256, 1) void gemm_l0(const float* __restrict__ x, int ck) {
    extern __shared__ __align__(16) float wl[];   // [88][256]
    const int tid = threadIdx.x;
    for (int i = tid; i < (I_ * G4H) / 4; i += 256)
        ((float4*)wl)[i] = ((const float4*)g_wp)[i];
    __syncthreads();

    const int j  = tid & 63;
    const int wv = __builtin_amdgcn_readfirstlane(tid >> 6);

    for (int p = 0; p < 8; ++p) {
        const int qb = (blockIdx.x << 8) + (p << 5) + (wv << 3);
        const float* xr[8];
#pragma unroll
        for (int m = 0; m < 8; ++m) {
            const int q = qb + m;
            const long in_row = (long)(q & (B_ - 1)) * T_ + ck * TC + (q >> 11);
            xr[m] = x + (size_t)in_row * I_;
        }
        float4 acc[8];
#pragma unroll
        for (int m = 0; m < 8; ++m) acc[m] = make_float4(0.f, 0.f, 0.f, 0.f);

#pragma unroll 2
        for (int k = 0; k < I_; ++k) {
            const float4 w4 = *(const float4*)&wl[(k << 8) + (j << 2)];
#pragma unroll
            for (int m = 0; m < 8; ++m) {
                const float xv = xr[m][k];
                acc[m].x += w4.x * xv; acc[m].y += w4.y * xv;
                acc[m].z += w4.z * xv; acc[m].w += w4.w * xv;
            }
        }
#pragma unroll
        for (int m = 0; m < 8; ++m) {
            float* o = g_gpre + (size_t)(qb + m) * G4H + j;
            o[0]   = acc[m].x;   // gate i
            o[64]  = acc[m].y;   // gate f
            o[128] = acc[m].z;   // gate g
            o[192] = acc[m].w;   // gate o
        }
    }
}

// -------- layer-1 chunk GEMM: gpre[q][g*64+h] = ysc[q] @ Wih1^T --------
__global__ __launch_bounds__(256, 1) void gemm_l1() {
    extern __shared__ __align__(16) float wl[];   // [64][256]
    const int tid = threadIdx.x;
    for (int i = tid; i < (H_ * G4H) / 4; i += 256)
        ((float4*)wl)[i] = ((const float4*)(g_wp + I_ * G4H))[i];
    __syncthreads();

    const int j  = tid & 63;
    const int wv = __builtin_amdgcn_readfirstlane(tid >> 6);

    for (int p = 0; p < 8; ++p) {
        const int qb = (blockIdx.x << 8) + (p << 5) + (wv << 3);
        const float* xr[8];
#pragma unroll
        for (int m = 0; m < 8; ++m) xr[m] = g_ysc + (size_t)(qb + m) * H_;

        float4 acc[8];
#pragma unroll
        for (int m = 0; m < 8; ++m) acc[m] = make_float4(0.f, 0.f, 0.f, 0.f);

#pragma unroll 2
        for (int k = 0; k < H_; ++k) {
            const float4 w4 = *(const float4*)&wl[(k << 8) + (j << 2)];
#pragma unroll
            for (int m = 0; m < 8; ++m) {
                const float xv = xr[m][k];
                acc[m].x += w4.x * xv; acc[m].y += w4.y * xv;
                acc[m].z += w4.z * xv; acc[m].w += w4.w * xv;
            }
        }
#pragma unroll
        for (int m = 0; m < 8; ++m) {
            float* o = g_gpre + (size_t)(qb + m) * G4H + j;
            o[0]   = acc[m].x;
            o[64]  = acc[m].y;
            o[128] = acc[m].z;
            o[192] = acc[m].w;
        }
    }
}

// -------- recurrence: 4 rows per 256-thread block --------
// Wave g computes gate g for rows r0..r0+3 (outer product over k, W_hh row in
// VGPRs, h broadcast from hl[k][r]). Combine phase: thread (r = g, j) owns
// c[r][j]; xch reads are conflict-free b32 (lanes consecutive in j).
__global__ __launch_bounds__(256, 1) void lstm_rec(const float* __restrict__ whh,
                                                   const float* __restrict__ bih,
                                                   const float* __restrict__ bhh,
                                                   const int layer, const int ck,
                                                   const float* __restrict__ fcw,
                                                   const float* __restrict__ fcb,
                                                   float* __restrict__ out) {
    __shared__ __align__(16) float hl[H_][NBR];   // [k][r]
    __shared__ float xch[NBR][4][H_];             // [r][gate][j]

    const int tid = threadIdx.x;
    const int j   = tid & 63;
    const int g   = tid >> 6;          // wave index = gate; also combiner row
    const int r0  = blockIdx.x * NBR;

    // W_hh row (g*64+j) into VGPRs: 64 floats = 16 float4
    float4 w[16];
    const float* wrow = whh + (size_t)(g * H_ + j) * H_;
#pragma unroll
    for (int kk = 0; kk < 16; ++kk) w[kk] = ((const float4*)wrow)[kk];

    const float bias = bih[g * H_ + j] + bhh[g * H_ + j];

    // init hl[k][r] (flat tid: k=tid>>2, r=tid&3) and c (thread owns (r=g, j))
    ((float*)hl)[tid] = ck ? g_h[layer][(size_t)(r0 + (tid & 3)) * H_ + (tid >> 2)] : 0.f;
    float c = ck ? g_c[layer][(size_t)(r0 + g) * H_ + j] : 0.f;

    // gpre: wave g, lane j, rows r0..r0+3; + tl*B_*G4H per step
    const float* gp = g_gpre + (size_t)r0 * G4H + g * H_ + j;
    float p0 = gp[0 * G4H], p1 = gp[1 * G4H], p2 = gp[2 * G4H], p3 = gp[3 * G4H];
    __syncthreads();

    for (int tl = 0; tl < TC; ++tl) {
        float a0 = bias + p0, a1 = bias + p1, a2 = bias + p2, a3 = bias + p3;
#pragma unroll
        for (int kk = 0; kk < 16; ++kk) {
            const float4 wv4 = w[kk];
            const float4 h0 = *(const float4*)&hl[(kk << 2) + 0][0];
            a0 += wv4.x * h0.x; a1 += wv4.x * h0.y; a2 += wv4.x * h0.z; a3 += wv4.x * h0.w;
            const float4 h1 = *(const float4*)&hl[(kk << 2) + 1][0];
            a0 += wv4.y * h1.x; a1 += wv4.y * h1.y; a2 += wv4.y * h1.z; a3 += wv4.y * h1.w;
            const float4 h2 = *(const float4*)&hl[(kk << 2) + 2][0];
            a0 += wv4.z * h2.x; a1 += wv4.z * h2.y; a2 += wv4.z * h2.z; a3 += wv4.z * h2.w;
            const float4 h3 = *(const float4*)&hl[(kk << 2) + 3][0];
            a0 += wv4.w * h3.x; a1 += wv4.w * h3.y; a2 += wv4.w * h3.z; a3 += wv4.w * h3.w;
        }
        // prefetch next step's gpre
        if (tl + 1 < TC) {
            const float* gn = gp + (size_t)(tl + 1) * B_ * G4H;
            p0 = gn[0 * G4H]; p1 = gn[1 * G4H]; p2 = gn[2 * G4H]; p3 = gn[3 * G4H];
        }
        if (g == 2) {
            xch[0][g][j] = tanh_f(a0); xch[1][g][j] = tanh_f(a1);
            xch[2][g][j] = tanh_f(a2); xch[3][g][j] = tanh_f(a3);
        } else {
            xch[0][g][j] = sigmoid_f(a0); xch[1][g][j] = sigmoid_f(a1);
            xch[2][g][j] = sigmoid_f(a2); xch[3][g][j] = sigmoid_f(a3);
        }
        __syncthreads();

        // combine: thread (r=g, j)
        {
            const float iv = xch[g][0][j], fv = xch[g][1][j];
            const float gv = xch[g][2][j], ov = xch[g][3][j];
            c = fv * c + iv * gv;
            const float h = ov * tanh_f(c);
            hl[j][g] = h;
            if (layer == 0) g_ysc[((size_t)tl * B_ + (r0 + g)) * H_ + j] = h;
        }
        __syncthreads();
    }

    // persist state: thread (r=g, j)
    g_h[layer][(size_t)(r0 + g) * H_ + j] = hl[j][g];
    g_c[layer][(size_t)(r0 + g) * H_ + j] = c;

    if (layer == 1 && ck == NCK - 1 && j < O_) {
        float s = fcb[j];
        const float* wr = fcw + j * H_;
#pragma unroll
        for (int k = 0; k < H_; ++k) s += hl[k][g] * wr[k];
        out[(size_t)(r0 + g) * O_ + j] = s;
    }
}

extern "C" void kernel_launch(void* const* d_in, const int* in_sizes, int n_in,
                              void* d_out, int out_size, void* d_ws, size_t ws_size,
                              hipStream_t stream) {
    const float* x    = (const float*)d_in[0];
    const float* wih0 = (const float*)d_in[1];
    const float* whh0 = (const float*)d_in[2];
    const float* bih0 = (const float*)d_in[3];
    const float* bhh0 = (const float*)d_in[4];
    const float* wih1 = (const float*)d_in[5];
    const float* whh1 = (const float*)d_in[6];
    const float* bih1 = (const float*)d_in[7];
    const float* bhh1 = (const float*)d_in[8];
    const float* fcw  = (const float*)d_in[9];
    const float* fcb  = (const float*)d_in[10];
    float* out = (float*)d_out;

    const int lds0 = I_ * G4H * 4;   // 90112
    const int lds1 = H_ * G4H * 4;   // 65536
    hipFuncSetAttribute((const void*)gemm_l0, hipFuncAttributeMaxDynamicSharedMemorySize, lds0);
    hipFuncSetAttribute((const void*)gemm_l1, hipFuncAttributeMaxDynamicSharedMemorySize, lds1);

    prep_weights<<<dim3(152), dim3(256), 0, stream>>>(wih0, wih1);

    for (int ck = 0; ck < NCK; ++ck) {
        gemm_l0<<<dim3(CR / 256), dim3(256), lds0, stream>>>(x, ck);
        lstm_rec<<<dim3(B_ / NBR), dim3(256), 0, stream>>>(whh0, bih0, bhh0, 0, ck, fcw, fcb, out);
        gemm_l1<<<dim3(CR / 256), dim3(256), lds1, stream>>>();
        lstm_rec<<<dim3(B_ / NBR), dim3(256), 0, stream>>>(whh1, bih1, bhh1, 1, ck, fcw, fcb, out);
    }
}